// Round 3
// baseline (147.590 us; speedup 1.0000x reference)
//
#include <hip/hip_runtime.h>
#include <math.h>

namespace {
constexpr int RADIUS = 9;
constexpr float EPSV = 1e-5f;
constexpr int N_ = 2, C_ = 64, H_ = 128, W_ = 192;
constexpr int HW  = H_ * W_;            // 24576
constexpr int CHW = C_ * HW;
constexpr int NOFF = RADIUS * RADIUS;   // 81
constexpr size_t OUT1 = (size_t)N_ * NOFF * HW;

constexpr int YB = 8, XB = 64;          // spatial tile per block (one n,i)
constexpr int NT = 512;                 // 4 c-groups x (8 rows x 16 chunks)
constexpr int CPG = 16;                 // channels per c-group
constexpr int CB = 2;                   // channels staged per group per round
constexpr int ROUNDS = CPG / CB;        // 8
constexpr int MS = 80, MCH = 20;        // map halo cols (x0-12 .. x0+67), float4 chunks
constexpr int ITEMS = 4 * CB * YB * MCH;   // 1280 float4 staged per round
}

// ---------------------------------------------------------------------------
// Single fused kernel: raw local correlation + on-the-fly channel L2 norms.
//   dotRaw[p,(i,j)] = sum_c map[c, clamp(p+(i,j)-9)] * img[c, p]
//   out_diss = invI[p] * dotRaw
//   out_cos  = 1 - invM[p'] * invI[p] * dotRaw
// block: fixed (n,i); 8x64 pixels; 4 c-groups of 16 channels each; LDS reduce.
// ---------------------------------------------------------------------------
__global__ __launch_bounds__(NT, 6)
void corr_fused(const float* __restrict__ img,
                const float* __restrict__ mp,
                float* __restrict__ out) {
    __shared__ float sMap[4 * CB * YB * MS];   // 5120 floats; reused as reduce scratch
    __shared__ float sInvM[YB * MS];           // 640 floats

    const int bz  = blockIdx.z;                // n*9 + i
    const int n   = bz / RADIUS;
    const int iOff = bz - n * RADIUS;
    const int y0 = blockIdx.y * YB;
    const int x0 = blockIdx.x * XB;
    const int tid = threadIdx.x;
    const int cg  = tid >> 7;                  // c-group 0..3
    const int rem = tid & 127;
    const int ty  = rem >> 4;                  // 0..7
    const int t   = rem & 15;                  // 0..15
    const int ybase = y0 + iOff - RADIUS;

    const float* imgN = img + (size_t)n * CHW;
    const float* mapN = mp  + (size_t)n * CHW;

    float acc[4][RADIUS];
#pragma unroll
    for (int p = 0; p < 4; ++p)
#pragma unroll
        for (int j = 0; j < RADIUS; ++j) acc[p][j] = 0.f;
    float si[4] = {0.f, 0.f, 0.f, 0.f};        // img^2 partial (this cg's channels)
    float4 smAcc[3];                            // map^2 partials for owned staging slots
#pragma unroll
    for (int it = 0; it < 3; ++it) { smAcc[it].x = smAcc[it].y = smAcc[it].z = smAcc[it].w = 0.f; }

    for (int ri = 0; ri < ROUNDS; ++ri) {
        __syncthreads();
        // ---- stage map halo: 1280 float4, fixed idx->slot mapping each round ----
#pragma unroll
        for (int it = 0; it < 3; ++it) {
            int idx = it * NT + tid;
            if (idx < ITEMS) {
                int g  = idx / 320;
                int r2 = idx - g * 320;
                int c  = (r2 >= 160) ? 1 : 0;
                int r3 = r2 - c * 160;
                int r  = r3 / 20;
                int ch = r3 - r * 20;
                int chnl = g * CPG + ri * CB + c;
                int gy  = min(max(ybase + r, 0), H_ - 1);
                int gxs = x0 - 12 + 4 * ch;
                const float* src = mapN + (size_t)chnl * HW + (size_t)gy * W_;
                float4 v;
                if (gxs >= 0 && gxs <= W_ - 4) {
                    v = *(const float4*)(src + gxs);
                } else {
                    v.x = src[min(max(gxs + 0, 0), W_ - 1)];
                    v.y = src[min(max(gxs + 1, 0), W_ - 1)];
                    v.z = src[min(max(gxs + 2, 0), W_ - 1)];
                    v.w = src[min(max(gxs + 3, 0), W_ - 1)];
                }
                *(float4*)&sMap[((g * CB + c) * YB + r) * MS + 4 * ch] = v;
                smAcc[it].x = fmaf(v.x, v.x, smAcc[it].x);
                smAcc[it].y = fmaf(v.y, v.y, smAcc[it].y);
                smAcc[it].z = fmaf(v.z, v.z, smAcc[it].z);
                smAcc[it].w = fmaf(v.w, v.w, smAcc[it].w);
            }
        }
        __syncthreads();
        // ---- compute: per channel, img from global (registers), map from LDS ----
#pragma unroll
        for (int c = 0; c < CB; ++c) {
            int chnl = cg * CPG + ri * CB + c;
            float4 a4 = *(const float4*)(imgN + (size_t)chnl * HW +
                                         (size_t)(y0 + ty) * W_ + x0 + 4 * t);
            const float* mb = &sMap[((cg * CB + c) * YB + ty) * MS + 4 * t];
            float w[16];
            *(float4*)&w[0]  = *(const float4*)(mb);
            *(float4*)&w[4]  = *(const float4*)(mb + 4);
            *(float4*)&w[8]  = *(const float4*)(mb + 8);
            *(float4*)&w[12] = *(const float4*)(mb + 12);
            float a[4] = {a4.x, a4.y, a4.z, a4.w};
            si[0] = fmaf(a[0], a[0], si[0]);
            si[1] = fmaf(a[1], a[1], si[1]);
            si[2] = fmaf(a[2], a[2], si[2]);
            si[3] = fmaf(a[3], a[3], si[3]);
#pragma unroll
            for (int p = 0; p < 4; ++p)
#pragma unroll
                for (int j = 0; j < RADIUS; ++j)
                    acc[p][j] = fmaf(w[p + j + 3], a[p], acc[p][j]);
        }
    }

    // ==== epilogue ====
    __syncthreads();                    // done reading staged map
    // ---- map-norm partial reduce: 8 partials per halo pixel ----
    float4* red4 = (float4*)sMap;       // 1280 float4
#pragma unroll
    for (int it = 0; it < 3; ++it) {
        int idx = it * NT + tid;
        if (idx < ITEMS) {
            int g  = idx / 320;
            int r2 = idx - g * 320;
            int c  = (r2 >= 160) ? 1 : 0;
            int r3 = r2 - c * 160;      // r*20+ch in [0,160)
            red4[(g * CB + c) * 160 + r3] = smAcc[it];
        }
    }
    __syncthreads();
    if (tid < 160) {
        float4 s = red4[tid];
#pragma unroll
        for (int p2 = 1; p2 < 8; ++p2) {
            float4 v = red4[p2 * 160 + tid];
            s.x += v.x; s.y += v.y; s.z += v.z; s.w += v.w;
        }
        float4 inv;
        inv.x = 1.f / (sqrtf(s.x) + EPSV);
        inv.y = 1.f / (sqrtf(s.y) + EPSV);
        inv.z = 1.f / (sqrtf(s.z) + EPSV);
        inv.w = 1.f / (sqrtf(s.w) + EPSV);
        *(float4*)&sInvM[4 * tid] = inv;
    }
    __syncthreads();
    // ---- acc tree reduce across c-groups: g3 -> g2 -> g1 -> g0 ----
    float* red = sMap;                  // 128 threads x 40 floats = 5120
    if (cg == 3) {
        float* dst = &red[rem * 40];
#pragma unroll
        for (int p = 0; p < 4; ++p)
#pragma unroll
            for (int j = 0; j < RADIUS; ++j) dst[p * 9 + j] = acc[p][j];
#pragma unroll
        for (int p = 0; p < 4; ++p) dst[36 + p] = si[p];
    }
    __syncthreads();
    if (cg == 2) {
        float* d2 = &red[rem * 40];
#pragma unroll
        for (int p = 0; p < 4; ++p)
#pragma unroll
            for (int j = 0; j < RADIUS; ++j) { acc[p][j] += d2[p * 9 + j]; d2[p * 9 + j] = acc[p][j]; }
#pragma unroll
        for (int p = 0; p < 4; ++p) { si[p] += d2[36 + p]; d2[36 + p] = si[p]; }
    }
    __syncthreads();
    if (cg == 1) {
        float* d2 = &red[rem * 40];
#pragma unroll
        for (int p = 0; p < 4; ++p)
#pragma unroll
            for (int j = 0; j < RADIUS; ++j) { acc[p][j] += d2[p * 9 + j]; d2[p * 9 + j] = acc[p][j]; }
#pragma unroll
        for (int p = 0; p < 4; ++p) { si[p] += d2[36 + p]; d2[36 + p] = si[p]; }
    }
    __syncthreads();
    if (cg == 0) {
        float* d2 = &red[rem * 40];
#pragma unroll
        for (int p = 0; p < 4; ++p)
#pragma unroll
            for (int j = 0; j < RADIUS; ++j) { acc[p][j] += d2[p * 9 + j]; d2[p * 9 + j] = acc[p][j]; }
#pragma unroll
        for (int p = 0; p < 4; ++p) { si[p] += d2[36 + p]; d2[36 + p] = si[p]; }
    }
    __syncthreads();
    // ---- redistribute j-subsets to all groups and store scaled outputs ----
    const float* fin = &red[rem * 40];
    float invI_[4];
#pragma unroll
    for (int p = 0; p < 4; ++p) invI_[p] = 1.f / (sqrtf(fin[36 + p]) + EPSV);
    const int y  = y0 + ty;
    const int xb = x0 + 4 * t;
    float* ocB = out + (size_t)n * NOFF * HW + (size_t)(iOff * RADIUS) * HW
               + (size_t)y * W_ + xb;
    const int j0tab[4]  = {0, 3, 5, 7};
    const int cnttab[4] = {3, 2, 2, 2};
    const int j0 = j0tab[cg], cnt = cnttab[cg];
    for (int jj = 0; jj < cnt; ++jj) {
        int j = j0 + jj;
        float4 vd, vc;
        vd.x = fin[0 * 9 + j] * invI_[0];
        vd.y = fin[1 * 9 + j] * invI_[1];
        vd.z = fin[2 * 9 + j] * invI_[2];
        vd.w = fin[3 * 9 + j] * invI_[3];
        const float* wm = &sInvM[ty * MS + 4 * t + j + 3];
        vc.x = 1.f - vd.x * wm[0];
        vc.y = 1.f - vd.y * wm[1];
        vc.z = 1.f - vd.z * wm[2];
        vc.w = 1.f - vd.w * wm[3];
        *(float4*)(ocB + (size_t)j * HW) = vc;
        *(float4*)(ocB + OUT1 + (size_t)j * HW) = vd;
    }
}

extern "C" void kernel_launch(void* const* d_in, const int* in_sizes, int n_in,
                              void* d_out, int out_size, void* d_ws, size_t ws_size,
                              hipStream_t stream) {
    const float* img = (const float*)d_in[0];
    const float* mp  = (const float*)d_in[1];
    float* out = (float*)d_out;
    dim3 grid(W_ / XB, H_ / YB, N_ * RADIUS);   // 3 x 16 x 18 = 864 blocks
    corr_fused<<<grid, NT, 0, stream>>>(img, mp, out);
}

// Round 4
// 65.526 us; speedup vs baseline: 2.2524x; 2.2524x over previous
//
#include <hip/hip_runtime.h>
#include <math.h>

namespace {
constexpr int RADIUS = 9;
constexpr float EPSV = 1e-5f;
constexpr int N_ = 2, C_ = 64, H_ = 128, W_ = 192;
constexpr int HW  = H_ * W_;            // 24576
constexpr int CHW = C_ * HW;
constexpr size_t OUT1 = (size_t)N_ * 81 * HW;

constexpr int XT = 32, YT = 4;          // spatial tile
constexpr int NIG = 3;                  // i-values per block (i-triple)
constexpr int NT = 384;                 // 4 cg x 3 il x 4 ty x 8 xc
constexpr int MROWS = 6;                // YT + NIG - 1
constexpr int MCOLS = 44;               // XT + 12 (col0 = x0-12), 11 float4 chunks
constexpr int ISTR  = 36;               // img LDS row stride (pad)
// LDS float offsets
constexpr int OFF_INVM = 0;                       // 6*44 = 264
constexpr int OFF_MAP  = 264;                     // 16 planes * 264 = 4224
constexpr int OFF_IMG  = 264 + 16 * MROWS * MCOLS; // 4488; 16 planes * 144 = 2304
constexpr int LDS_FLOATS = OFF_IMG + 16 * YT * ISTR; // 6792 -> 27168 B
}

// ---------------------------------------------------------------------------
// Kernel 1: per-pixel inverse channel L2 norms
// ---------------------------------------------------------------------------
__global__ void norms_kernel(const float* __restrict__ img,
                             const float* __restrict__ mp,
                             float* __restrict__ invI,
                             float* __restrict__ invM) {
    int q = blockIdx.x * blockDim.x + threadIdx.x;
    if (q >= N_ * HW) return;
    int n = q / HW;
    int rem = q - n * HW;
    const float* pi = img + (size_t)n * CHW + rem;
    const float* pm = mp  + (size_t)n * CHW + rem;
    float si = 0.f, sm = 0.f;
#pragma unroll 8
    for (int c = 0; c < C_; ++c) {
        float a = pi[c * HW];
        float b = pm[c * HW];
        si = fmaf(a, a, si);
        sm = fmaf(b, b, sm);
    }
    invI[q] = 1.f / (sqrtf(si) + EPSV);
    invM[q] = 1.f / (sqrtf(sm) + EPSV);
}

// ---------------------------------------------------------------------------
// Kernel 2: raw correlation + scaled epilogue.
//   dotRaw[p,(i,j)] = sum_c map[c, clamp(p+(i,j)-9)] * img[c, p]
//   out_diss = invI[p] * dotRaw ;  out_cos = 1 - invM[p'] * out_diss
// Block: (n, i-triple, 4x32 px). 4 c-groups of 16 ch, LDS serial reduce.
// ---------------------------------------------------------------------------
__global__ __launch_bounds__(NT, 4)
void corr_kernel(const float* __restrict__ img,
                 const float* __restrict__ mp,
                 const float* __restrict__ invIg,
                 const float* __restrict__ invMg,
                 float* __restrict__ out) {
    __shared__ float smem[LDS_FLOATS];
    float* sInvM = &smem[OFF_INVM];
    float* sMap  = &smem[OFF_MAP];
    float* sImg  = &smem[OFF_IMG];

    const int bz = blockIdx.z;             // n*3 + ig
    const int n  = bz / NIG;
    const int ig = bz - n * NIG;
    const int y0 = blockIdx.y * YT;
    const int x0 = blockIdx.x * XT;
    const int tid = threadIdx.x;
    const int cg = tid / 96;               // 0..3
    const int t96 = tid - cg * 96;
    const int il = t96 >> 5;               // 0..2
    const int r32 = t96 & 31;
    const int ty = r32 >> 3;               // 0..3
    const int xc = r32 & 7;                // 0..7
    const int ybase = y0 + NIG * ig - RADIUS;

    const float* imgN = img + (size_t)n * CHW;
    const float* mapN = mp  + (size_t)n * CHW;

    // ---- stage invM halo (66 float4) once; consumed only in epilogue ----
    if (tid < 66) {
        int r  = tid / 11;
        int ch = tid - r * 11;
        int gy = min(max(ybase + r, 0), H_ - 1);
        int gxs = x0 - 12 + 4 * ch;
        const float* src = invMg + n * HW + (size_t)gy * W_;
        float4 v;
        if (gxs >= 0) {
            v = *(const float4*)(src + gxs);
        } else {
            v.x = src[max(gxs + 0, 0)];
            v.y = src[max(gxs + 1, 0)];
            v.z = src[max(gxs + 2, 0)];
            v.w = src[max(gxs + 3, 0)];
        }
        *(float4*)&sInvM[r * MCOLS + 4 * ch] = v;
    }

    float acc[4][RADIUS];
#pragma unroll
    for (int p = 0; p < 4; ++p)
#pragma unroll
        for (int j = 0; j < RADIUS; ++j) acc[p][j] = 0.f;

    // per-thread LDS read offsets (floats)
    const int mapRd = (ty + il) * MCOLS + 4 * xc;
    const int imgRd = ty * ISTR + 4 * xc;

    for (int ri = 0; ri < 4; ++ri) {       // 16 channels staged per round
        __syncthreads();
        // ---- stage map: 16 planes x 6 rows x 11 chunks = 1056 float4 ----
#pragma unroll
        for (int it = 0; it < 3; ++it) {
            int idx = it * NT + tid;
            if (idx < 1056) {
                int pl  = idx / 66;
                int r66 = idx - pl * 66;
                int r   = r66 / 11;
                int ch  = r66 - r * 11;
                int chnl = (pl >> 2) * 16 + ri * 4 + (pl & 3);
                int gy  = min(max(ybase + r, 0), H_ - 1);
                int gxs = x0 - 12 + 4 * ch;
                const float* src = mapN + (size_t)chnl * HW + (size_t)gy * W_;
                float4 v;
                if (gxs >= 0) {
                    v = *(const float4*)(src + gxs);
                } else {
                    v.x = src[max(gxs + 0, 0)];
                    v.y = src[max(gxs + 1, 0)];
                    v.z = src[max(gxs + 2, 0)];
                    v.w = src[max(gxs + 3, 0)];
                }
                *(float4*)&sMap[pl * (MROWS * MCOLS) + r * MCOLS + 4 * ch] = v;
            }
        }
        // ---- stage img: 16 planes x 4 rows x 8 chunks = 512 float4 ----
#pragma unroll
        for (int it = 0; it < 2; ++it) {
            int idx = it * NT + tid;
            if (idx < 512) {
                int pl = idx >> 5;
                int r5 = idx & 31;
                int r  = r5 >> 3;
                int k  = r5 & 7;
                int chnl = (pl >> 2) * 16 + ri * 4 + (pl & 3);
                float4 v = *(const float4*)(imgN + (size_t)chnl * HW +
                                            (size_t)(y0 + r) * W_ + x0 + 4 * k);
                *(float4*)&sImg[pl * (YT * ISTR) + r * ISTR + 4 * k] = v;
            }
        }
        __syncthreads();
        // ---- compute: 4 channels for this cg ----
#pragma unroll
        for (int c = 0; c < 4; ++c) {
            int pl = (cg << 2) + c;
            const float* mb = &sMap[pl * (MROWS * MCOLS) + mapRd];
            float4 a4 = *(const float4*)&sImg[pl * (YT * ISTR) + imgRd];
            float w[16];
            *(float4*)&w[0]  = *(const float4*)(mb);
            *(float4*)&w[4]  = *(const float4*)(mb + 4);
            *(float4*)&w[8]  = *(const float4*)(mb + 8);
            *(float4*)&w[12] = *(const float4*)(mb + 12);
            float a[4] = {a4.x, a4.y, a4.z, a4.w};
#pragma unroll
            for (int p = 0; p < 4; ++p)
#pragma unroll
                for (int j = 0; j < RADIUS; ++j)
                    acc[p][j] = fmaf(w[p + j + 3], a[p], acc[p][j]);
        }
    }

    // ==== epilogue: serial 4-way c-reduce in LDS (overlay on sMap) ====
    __syncthreads();                       // all compute reads of sMap done
    float* mine = &sMap[t96 * 44];         // 96 threads x 44-float slots (stride 44: conflict-spread)
    // layout per slot: j-th float4 = {acc[0][j],acc[1][j],acc[2][j],acc[3][j]}
    if (cg == 3) {
#pragma unroll
        for (int j = 0; j < RADIUS; ++j) {
            float4 v = {acc[0][j], acc[1][j], acc[2][j], acc[3][j]};
            *(float4*)&mine[4 * j] = v;
        }
    }
    __syncthreads();
    if (cg == 2) {
#pragma unroll
        for (int j = 0; j < RADIUS; ++j) {
            float4 v = *(const float4*)&mine[4 * j];
            v.x += acc[0][j]; v.y += acc[1][j]; v.z += acc[2][j]; v.w += acc[3][j];
            *(float4*)&mine[4 * j] = v;
        }
    }
    __syncthreads();
    if (cg == 1) {
#pragma unroll
        for (int j = 0; j < RADIUS; ++j) {
            float4 v = *(const float4*)&mine[4 * j];
            v.x += acc[0][j]; v.y += acc[1][j]; v.z += acc[2][j]; v.w += acc[3][j];
            *(float4*)&mine[4 * j] = v;
        }
    }
    __syncthreads();
    if (cg == 0) {
#pragma unroll
        for (int j = 0; j < RADIUS; ++j) {
            float4 v = *(const float4*)&mine[4 * j];
            v.x += acc[0][j]; v.y += acc[1][j]; v.z += acc[2][j]; v.w += acc[3][j];
            *(float4*)&mine[4 * j] = v;
        }
    }
    __syncthreads();

    // ---- all threads: store a disjoint j-subset of this (il, px) slot ----
    const int y = y0 + ty;
    const int xb = x0 + 4 * xc;
    float4 vI = *(const float4*)(invIg + n * HW + (size_t)y * W_ + xb);
    const int i = NIG * ig + il;
    float* ocB = out + (size_t)n * 81 * HW + (size_t)y * W_ + xb;
    const int j0  = (cg == 0) ? 0 : (cg == 1) ? 3 : (cg == 2) ? 5 : 7;
    const int cnt = (cg == 0) ? 3 : 2;
    const float* wmB = &sInvM[(ty + il) * MCOLS + 4 * xc + 3];
    for (int jj = 0; jj < cnt; ++jj) {
        int j = j0 + jj;
        float4 s = *(const float4*)&mine[4 * j];
        float4 vd, vc;
        vd.x = s.x * vI.x;
        vd.y = s.y * vI.y;
        vd.z = s.z * vI.z;
        vd.w = s.w * vI.w;
        vc.x = 1.f - vd.x * wmB[j + 0];
        vc.y = 1.f - vd.y * wmB[j + 1];
        vc.z = 1.f - vd.z * wmB[j + 2];
        vc.w = 1.f - vd.w * wmB[j + 3];
        size_t o = (size_t)(i * RADIUS + j) * HW;
        *(float4*)(ocB + o) = vc;
        *(float4*)(ocB + OUT1 + o) = vd;
    }
}

extern "C" void kernel_launch(void* const* d_in, const int* in_sizes, int n_in,
                              void* d_out, int out_size, void* d_ws, size_t ws_size,
                              hipStream_t stream) {
    const float* img = (const float*)d_in[0];
    const float* mp  = (const float*)d_in[1];
    float* out  = (float*)d_out;
    float* invI = (float*)d_ws;
    float* invM = invI + N_ * HW;

    int npix = N_ * HW;
    norms_kernel<<<(npix + 255) / 256, 256, 0, stream>>>(img, mp, invI, invM);

    dim3 grid(W_ / XT, H_ / YT, N_ * NIG);   // 6 x 32 x 6 = 1152 blocks
    corr_kernel<<<grid, NT, 0, stream>>>(img, mp, invI, invM, out);
}